// Round 10
// baseline (374.510 us; speedup 1.0000x reference)
//
#include <hip/hip_runtime.h>
#include <hip/hip_bf16.h>
#include <stdint.h>

#define NIMG 96
#define N 512
#define IMG (N*N)
#define OUT_PLANE ((long long)NIMG * IMG)

typedef __attribute__((ext_vector_type(8))) _Float16 f16x8;
typedef __attribute__((ext_vector_type(4))) float f32x4;
typedef __attribute__((ext_vector_type(16))) float f32x16;
typedef unsigned short u16;

__device__ __forceinline__ u16 f2h(float v) {
    _Float16 h = (_Float16)v;
    return __builtin_bit_cast(u16, h);
}

__device__ __forceinline__ void gload16(const void* g, void* l) {
    __builtin_amdgcn_global_load_lds(
        (const __attribute__((address_space(1))) void*)g,
        (__attribute__((address_space(3))) void*)l, 16, 0, 0);
}

// ---------------------------------------------------------------------------
// conv_x: x fp32 -> Xcm f16 col-major; outLL = x (all-ones mask = identity).
// Blocks with flat id < 1024 also build D (f16, row- and col-major).
// ---------------------------------------------------------------------------
__global__ __launch_bounds__(256) void conv_x(const float* __restrict__ x,
                                              u16* __restrict__ Xcm,
                                              float* __restrict__ outLL,
                                              u16* __restrict__ Drm,
                                              u16* __restrict__ Dcm) {
    const int bid = blockIdx.x + (blockIdx.y << 4) + (blockIdx.z << 8);
    if (bid < 1024) {
        int idx = (bid << 8) + threadIdx.x;
        int k = idx >> 9, m = idx & 511;
        int r = ((2 * m + 1) * k) & 2047;          // exact angle reduction mod 4N
        float c = cospif((float)r * (1.0f / 1024.0f));
        float s = (k == 0) ? 0.04419417382415922f : 0.0625f;
        u16 h = f2h(c * s);
        Drm[(k << 9) + m] = h;
        Dcm[(m << 9) + k] = h;
    }

    __shared__ float t[32][33];
    const long long base = (long long)blockIdx.z * IMG;
    const int r0 = blockIdx.y * 32, c0 = blockIdx.x * 32;
    const int tr = threadIdx.x >> 3;
    const int tc = (threadIdx.x & 7) * 4;
    float4 v = *(const float4*)&x[base + (long long)(r0 + tr) * N + c0 + tc];
    *(float4*)&outLL[base + (long long)(r0 + tr) * N + c0 + tc] = v;
    t[tr][tc + 0] = v.x; t[tr][tc + 1] = v.y;
    t[tr][tc + 2] = v.z; t[tr][tc + 3] = v.w;
    __syncthreads();
    ushort4 h;
    h.x = f2h(t[tc + 0][tr]); h.y = f2h(t[tc + 1][tr]);
    h.z = f2h(t[tc + 2][tr]); h.w = f2h(t[tc + 3][tr]);
    *(ushort4*)&Xcm[base + (long long)(c0 + tr) * N + r0 + tc] = h;
}

// ===========================================================================
// GEMM engine (round-4/6 structure), inner math on mfma_f32_32x32x16_f16:
// 128x128 tile, BK=32, 4 waves (64x64 each = 2x2 of 32x32), dbuf LDS,
// global_load_lds width-16 staging. Per K-iter per wave: 8 MFMA (2i x 2j x
// 2 k-halves) vs 16 with the 16x16 shape -- same FLOPs, higher pipe ceiling
// (2382 vs 2075 TF) and half the issue slots. LDS layout and ds_read count
// unchanged (f16x8 at (row)*32 + h*16 + (lane>>5)*8, row = tile_base+lane&31).
// Fragment maps: A/B: row(col)=lane&31, k=(lane>>5)*8+e.
// C/D: col=lane&31, row=(reg&3)+8*(reg>>2)+4*(lane>>5)  [guide m74/m101].
// SW=1 swaps operands -> C^T in-register -> reg-groups = 4 consecutive C-cols
// -> float4/ushort4 row-major stores. SW=0 natural -> reg-groups = 4
// consecutive C-rows -> ushort4 col-major stores.
// C = A(row-major) * B(col-major storage: stored[n][k] = op(B)[k][n]).
// ===========================================================================
#define GEMM_DECLS                                                         \
    const int tid = threadIdx.x;                                           \
    const int wave = tid >> 6;                                             \
    const int lane = tid & 63;                                             \
    const int srow = lane >> 2;                                            \
    const int sc8  = (lane & 3) * 8;                                       \
    const int war  = wave * 32;                                            \
    const int lr   = lane & 31;                                            \
    const int kh8  = (lane >> 5) * 8;                                      \
    const int wr   = (wave >> 1) * 64;                                     \
    const int wc   = (wave & 1) * 64;                                      \
    const int rg4  = (lane >> 5) * 4;                                      \
    int aoff[2][2], boff[2][2];                                            \
    _Pragma("unroll")                                                      \
    for (int i = 0; i < 2; ++i)                                            \
        _Pragma("unroll")                                                  \
        for (int h = 0; h < 2; ++h) {                                      \
            aoff[i][h] = (wr + i * 32 + lr) * 32 + h * 16 + kh8;           \
            boff[i][h] = (wc + i * 32 + lr) * 32 + h * 16 + kh8;           \
        }                                                                  \
    f32x16 acc[2][2];                                                      \
    _Pragma("unroll")                                                      \
    for (int i = 0; i < 2; ++i)                                            \
        _Pragma("unroll")                                                  \
        for (int j = 0; j < 2; ++j)                                        \
            acc[i][j] = (f32x16)(0.0f);

#define GEMM_LOOP(Ab, lda, Bb, ldb, Keff, SW)                              \
    {                                                                      \
        auto stage = [&](int buf, int k0) {                                \
            _Pragma("unroll")                                              \
            for (int i = 0; i < 2; ++i) {                                  \
                int r = war + i * 16;                                      \
                gload16((Ab) + (long long)(m0 + r + srow) * (lda) + k0 + sc8, &As[buf][r * 32]); \
                gload16((Bb) + (long long)(n0 + r + srow) * (ldb) + k0 + sc8, &Bs[buf][r * 32]); \
            }                                                              \
        };                                                                 \
        auto compute = [&](int buf) {                                      \
            f16x8 af[2][2], bf[2][2];                                      \
            _Pragma("unroll")                                              \
            for (int i = 0; i < 2; ++i)                                    \
                _Pragma("unroll")                                          \
                for (int h = 0; h < 2; ++h) {                              \
                    af[i][h] = *(const f16x8*)&As[buf][aoff[i][h]];        \
                    bf[i][h] = *(const f16x8*)&Bs[buf][boff[i][h]];        \
                }                                                          \
            _Pragma("unroll")                                              \
            for (int i = 0; i < 2; ++i)                                    \
                _Pragma("unroll")                                          \
                for (int j = 0; j < 2; ++j)                                \
                    _Pragma("unroll")                                      \
                    for (int h = 0; h < 2; ++h) {                          \
                        if (SW)                                            \
                            acc[i][j] = __builtin_amdgcn_mfma_f32_32x32x16_f16(bf[j][h], af[i][h], acc[i][j], 0, 0, 0); \
                        else                                               \
                            acc[i][j] = __builtin_amdgcn_mfma_f32_32x32x16_f16(af[i][h], bf[j][h], acc[i][j], 0, 0, 0); \
                    }                                                      \
        };                                                                 \
        const int nb = (Keff) >> 5;                                        \
        stage(0, 0);                                                       \
        __syncthreads();                                                   \
        int cur = 0;                                                       \
        for (int t = 0; t < nb - 1; ++t) {                                 \
            stage(cur ^ 1, (t + 1) * 32);                                  \
            compute(cur);                                                  \
            __syncthreads();                                               \
            cur ^= 1;                                                      \
        }                                                                  \
        compute(cur);                                                      \
    }

// ---------------------------------------------------------------------------
// gemm16: EPI 0 = fp32 row-major (SW=1, float4 stores);
//         1 = f16 row-major (SW=1, ushort4 stores);
//         3 = f16 col-major + tri mask + fused Y2/Y3 + zero-tile skip (SW=0).
// ---------------------------------------------------------------------------
template<int EPI>
__global__ __launch_bounds__(256) void gemm16(
    const u16* __restrict__ A, long long sA, int lda,
    const u16* __restrict__ B, long long sB, int ldb,
    void* __restrict__ Cv, long long sC, int ldc,
    int K, int trilim,
    u16* __restrict__ Y2, u16* __restrict__ Y3)
{
    __shared__ u16 As[2][128 * 32];
    __shared__ u16 Bs[2][128 * 32];
    const int bz = blockIdx.z;
    const int m0 = blockIdx.y * 128;
    const int n0 = blockIdx.x * 128;

    if (EPI == 3 && (m0 + n0 > trilim)) return;   // fully-masked tile: never read downstream

    const u16* __restrict__ Ab = A + (long long)bz * sA;
    const u16* __restrict__ Bb = B + (long long)bz * sB;

    GEMM_DECLS
    GEMM_LOOP(Ab, lda, Bb, ldb, K, (EPI != 3))

    if (EPI == 0) {
        // swapped: lane&31 = C-row; reg-groups = 4 consecutive C-cols
        float* Cb = (float*)Cv + (long long)bz * sC;
        #pragma unroll
        for (int i = 0; i < 2; ++i)
            #pragma unroll
            for (int j = 0; j < 2; ++j) {
                int row = m0 + wr + i * 32 + lr;
                #pragma unroll
                for (int g = 0; g < 4; ++g) {
                    int c0 = n0 + wc + j * 32 + 8 * g + rg4;
                    float4 v = make_float4(acc[i][j][4 * g + 0], acc[i][j][4 * g + 1],
                                           acc[i][j][4 * g + 2], acc[i][j][4 * g + 3]);
                    *(float4*)&Cb[(long long)row * ldc + c0] = v;
                }
            }
    } else if (EPI == 1) {
        u16* Cb = (u16*)Cv + (long long)bz * sC;
        #pragma unroll
        for (int i = 0; i < 2; ++i)
            #pragma unroll
            for (int j = 0; j < 2; ++j) {
                int row = m0 + wr + i * 32 + lr;
                #pragma unroll
                for (int g = 0; g < 4; ++g) {
                    int c0 = n0 + wc + j * 32 + 8 * g + rg4;
                    ushort4 h;
                    h.x = f2h(acc[i][j][4 * g + 0]); h.y = f2h(acc[i][j][4 * g + 1]);
                    h.z = f2h(acc[i][j][4 * g + 2]); h.w = f2h(acc[i][j][4 * g + 3]);
                    *(ushort4*)&Cb[(long long)row * ldc + c0] = h;
                }
            }
    } else {
        // natural: lane&31 = C-col; reg-groups = 4 consecutive C-rows
        u16* Cb = (u16*)Cv + (long long)bz * sC;
        u16* Y2b = Y2 + (long long)bz * (256 * 256);
        u16* Y3b = Y3 + (long long)bz * (128 * 128);
        const bool doY2 = (m0 + n0 < 256);        // Y2 zero quadrant never read (kcap)
        #pragma unroll
        for (int i = 0; i < 2; ++i)
            #pragma unroll
            for (int j = 0; j < 2; ++j) {
                int c = n0 + wc + j * 32 + lr;
                #pragma unroll
                for (int g = 0; g < 4; ++g) {
                    int r0 = m0 + wr + i * 32 + 8 * g + rg4;
                    float v0 = ((r0 + 0) + c <= trilim) ? acc[i][j][4 * g + 0] : 0.0f;
                    float v1 = ((r0 + 1) + c <= trilim) ? acc[i][j][4 * g + 1] : 0.0f;
                    float v2 = ((r0 + 2) + c <= trilim) ? acc[i][j][4 * g + 2] : 0.0f;
                    float v3 = ((r0 + 3) + c <= trilim) ? acc[i][j][4 * g + 3] : 0.0f;
                    ushort4 h;
                    h.x = f2h(v0); h.y = f2h(v1); h.z = f2h(v2); h.w = f2h(v3);
                    *(ushort4*)&Cb[(long long)c * ldc + r0] = h;   // col-major 8B store
                    if (doY2 && r0 < 256 && c < 256) {
                        ushort4 h2;
                        h2.x = ((r0 + 0) + c <= 255) ? h.x : (u16)0;
                        h2.y = ((r0 + 1) + c <= 255) ? h.y : (u16)0;
                        h2.z = ((r0 + 2) + c <= 255) ? h.z : (u16)0;
                        h2.w = ((r0 + 3) + c <= 255) ? h.w : (u16)0;
                        *(ushort4*)&Y2b[(long long)c * 256 + r0] = h2;
                    }
                    if (r0 < 128 && c < 128) {
                        ushort4 h3;
                        h3.x = ((r0 + 0) + c <= 127) ? h.x : (u16)0;
                        h3.y = ((r0 + 1) + c <= 127) ? h.y : (u16)0;
                        h3.z = ((r0 + 2) + c <= 127) ? h.z : (u16)0;
                        h3.w = ((r0 + 3) + c <= 127) ? h.w : (u16)0;
                        *(ushort4*)&Y3b[(long long)c * 128 + r0] = h3;
                    }
                }
            }
    }
}

// ---------------------------------------------------------------------------
// invA: merged S3/S5/S7 (SW=0, col-major ushort4 epilogue).
// Flat blockIdx.x in [0,28): [0,16)=S3, [16,24)=S5, [24,28)=S7.
// A anti-triangular -> K early stop (Keff).
// ---------------------------------------------------------------------------
__global__ __launch_bounds__(256) void invA(
    const u16* __restrict__ Ycm, const u16* __restrict__ Y2,
    const u16* __restrict__ Y3, const u16* __restrict__ Dcm,
    u16* __restrict__ U, u16* __restrict__ U2, u16* __restrict__ U3)
{
    __shared__ u16 As[2][128 * 32];
    __shared__ u16 Bs[2][128 * 32];
    const int bz = blockIdx.z;
    const int id = blockIdx.x;

    const u16* __restrict__ Ab;
    u16* __restrict__ Cb;
    int lda, ldc, Keff, m0, n0;
    if (id < 16) {            // S3: U^T = Ym^T @ D   (M=512, K=512-m0)
        m0 = (id >> 2) * 128; n0 = (id & 3) * 128;
        Ab = Ycm + (long long)bz * IMG;     lda = 512;
        Cb = U   + (long long)bz * IMG;     ldc = 512;
        Keff = 512 - m0;
    } else if (id < 24) {     // S5: U2^T = Y2^T @ D[:256,:]  (M=256, K=256-m0)
        int t = id - 16;
        m0 = (t >> 2) * 128; n0 = (t & 3) * 128;
        Ab = Y2 + (long long)bz * 65536;    lda = 256;
        Cb = U2 + (long long)bz * 131072;   ldc = 256;
        Keff = 256 - m0;
    } else {                  // S7: U3^T = Y3^T @ D[:128,:]  (M=128, K=128)
        int t = id - 24;
        m0 = 0;              n0 = (t & 3) * 128;
        Ab = Y3 + (long long)bz * 16384;    lda = 128;
        Cb = U3 + (long long)bz * 65536;    ldc = 128;
        Keff = 128;
    }
    const u16* __restrict__ Bb = Dcm;
    const int ldb = 512;

    GEMM_DECLS
    GEMM_LOOP(Ab, lda, Bb, ldb, Keff, 0)

    #pragma unroll
    for (int i = 0; i < 2; ++i)
        #pragma unroll
        for (int j = 0; j < 2; ++j) {
            int c = n0 + wc + j * 32 + lr;
            #pragma unroll
            for (int g = 0; g < 4; ++g) {
                int r0 = m0 + wr + i * 32 + 8 * g + rg4;
                ushort4 h;
                h.x = f2h(acc[i][j][4 * g + 0]); h.y = f2h(acc[i][j][4 * g + 1]);
                h.z = f2h(acc[i][j][4 * g + 2]); h.w = f2h(acc[i][j][4 * g + 3]);
                *(ushort4*)&Cb[(long long)c * ldc + r0] = h;
            }
        }
}

// ---------------------------------------------------------------------------
// invB: merged S6/S8 (SW=1, float4 row-major epilogue). Flat id in [0,32):
// [0,16)=S6 (HL = U2 @ D[:256,:]), [16,32)=S8 (LH = U3 @ D[:128,:]).
// ---------------------------------------------------------------------------
__global__ __launch_bounds__(256) void invB(
    const u16* __restrict__ U2, const u16* __restrict__ U3,
    const u16* __restrict__ Dcm,
    float* __restrict__ outHL, float* __restrict__ outLH)
{
    __shared__ u16 As[2][128 * 32];
    __shared__ u16 Bs[2][128 * 32];
    const int bz = blockIdx.z;
    const int id = blockIdx.x;

    const u16* __restrict__ Ab;
    float* __restrict__ Cb;
    int lda, Keff, m0, n0;
    if (id < 16) {            // S6
        m0 = (id >> 2) * 128; n0 = (id & 3) * 128;
        Ab = U2 + (long long)bz * 131072;  lda = 256; Keff = 256;
        Cb = outHL + (long long)bz * IMG;
    } else {                  // S8
        int t = id - 16;
        m0 = (t >> 2) * 128; n0 = (t & 3) * 128;
        Ab = U3 + (long long)bz * 65536;   lda = 128; Keff = 128;
        Cb = outLH + (long long)bz * IMG;
    }
    const u16* __restrict__ Bb = Dcm;
    const int ldb = 512;
    const int ldc = 512;

    GEMM_DECLS
    GEMM_LOOP(Ab, lda, Bb, ldb, Keff, 1)

    #pragma unroll
    for (int i = 0; i < 2; ++i)
        #pragma unroll
        for (int j = 0; j < 2; ++j) {
            int row = m0 + wr + i * 32 + lr;
            #pragma unroll
            for (int g = 0; g < 4; ++g) {
                int c0 = n0 + wc + j * 32 + 8 * g + rg4;
                float4 v = make_float4(acc[i][j][4 * g + 0], acc[i][j][4 * g + 1],
                                       acc[i][j][4 * g + 2], acc[i][j][4 * g + 3]);
                *(float4*)&Cb[(long long)row * ldc + c0] = v;
            }
        }
}

// ---------------------------------------------------------------------------
// Orchestration (6 dispatches).
// ws (97MiB used): Drm @0 | Dcm @512K | Xcm/Ycm @1MiB (48MiB) | reg @49MiB:
//   T1 (S1->S2) then U (invA->S4)   [sequential lifetimes]
// outHH quarter = scratch until final S4: Y2 | Y3 | U2 | U3 (53.4MB < 100MB).
// Race-freedom: invA reads Y2/Y3, writes U2/U3 (disjoint ranges of outHH);
// invB reads U2/U3, writes outHL/outLH; S4 reads U (reg), writes outHH last.
// ---------------------------------------------------------------------------
extern "C" void kernel_launch(void* const* d_in, const int* in_sizes, int n_in,
                              void* d_out, int out_size, void* d_ws, size_t ws_size,
                              hipStream_t stream) {
    const float* x = (const float*)d_in[0];
    float* out = (float*)d_out;
    float* outLL = out + 0 * OUT_PLANE;
    float* outLH = out + 1 * OUT_PLANE;
    float* outHL = out + 2 * OUT_PLANE;
    float* outHH = out + 3 * OUT_PLANE;

    char* ws = (char*)d_ws;
    u16* Drm = (u16*)(ws);
    u16* Dcm = (u16*)(ws + 524288);
    u16* Xcm = (u16*)(ws + 1048576);
    u16* Ycm = Xcm;
    char* reg = ws + 51380224;
    u16* T1 = (u16*)reg;
    u16* U  = (u16*)reg;

    u16* Y2 = (u16*)outHH;                 // 96*256*256
    u16* Y3 = Y2 + 6291456;                // 96*128*128
    u16* U2 = Y3 + 1572864;                // 96*512*256
    u16* U3 = U2 + 12582912;               // 96*512*128

    const long long S = IMG;
    const int BIG = 1 << 30;

    // conv + D-build + LL copy
    conv_x<<<dim3(16, 16, NIMG), 256, 0, stream>>>(x, Xcm, outLL, Drm, Dcm);

    // S1: T1 = D @ X -> f16 row-major (swapped epilogue, ushort4 stores)
    gemm16<1><<<dim3(4, 4, NIMG), 256, 0, stream>>>(
        Drm, 0, 512, Xcm, S, 512, T1, S, 512, 512, BIG, nullptr, nullptr);
    // S2: Y = T1 @ D^T -> Ycm (tri511, fully-masked tiles skipped) + Y2/Y3
    gemm16<3><<<dim3(4, 4, NIMG), 256, 0, stream>>>(
        T1, S, 512, Drm, 0, 512, Ycm, S, 512, 512, 511, Y2, Y3);
    // invA: S3 + S5 + S7 -> U (reg), U2/U3 (outHH scratch)
    invA<<<dim3(28, 1, NIMG), 256, 0, stream>>>(Ycm, Y2, Y3, Dcm, U, U2, U3);
    // invB: S6 + S8 -> outHL, outLH (float4 stores)
    invB<<<dim3(32, 1, NIMG), 256, 0, stream>>>(U2, U3, Dcm, outHL, outLH);
    // S4: HH = U @ D -> outHH (overwrites scratch, last; float4 stores)
    gemm16<0><<<dim3(4, 4, NIMG), 256, 0, stream>>>(
        U, S, 512, Dcm, 0, 512, outHH, S, 512, 512, BIG, nullptr, nullptr);
}

// Round 11
// 343.677 us; speedup vs baseline: 1.0897x; 1.0897x over previous
//
#include <hip/hip_runtime.h>
#include <hip/hip_bf16.h>
#include <stdint.h>

#define NIMG 96
#define N 512
#define IMG (N*N)
#define OUT_PLANE ((long long)NIMG * IMG)

typedef __attribute__((ext_vector_type(8))) _Float16 f16x8;
typedef __attribute__((ext_vector_type(4))) float f32x4;
typedef unsigned short u16;

__device__ __forceinline__ u16 f2h(float v) {
    _Float16 h = (_Float16)v;
    return __builtin_bit_cast(u16, h);
}

__device__ __forceinline__ void gload16(const void* g, void* l) {
    __builtin_amdgcn_global_load_lds(
        (const __attribute__((address_space(1))) void*)g,
        (__attribute__((address_space(3))) void*)l, 16, 0, 0);
}

// ---------------------------------------------------------------------------
// conv_x: x fp32 -> Xcm f16 col-major; outLL = x (all-ones mask = identity).
// Blocks with flat id < 1024 also build D (f16, row- and col-major); D is
// only read by later dispatches.
// ---------------------------------------------------------------------------
__global__ __launch_bounds__(256) void conv_x(const float* __restrict__ x,
                                              u16* __restrict__ Xcm,
                                              float* __restrict__ outLL,
                                              u16* __restrict__ Drm,
                                              u16* __restrict__ Dcm) {
    const int bid = blockIdx.x + (blockIdx.y << 4) + (blockIdx.z << 8);
    if (bid < 1024) {
        int idx = (bid << 8) + threadIdx.x;
        int k = idx >> 9, m = idx & 511;
        int r = ((2 * m + 1) * k) & 2047;          // exact angle reduction mod 4N
        float c = cospif((float)r * (1.0f / 1024.0f));
        float s = (k == 0) ? 0.04419417382415922f : 0.0625f;
        u16 h = f2h(c * s);
        Drm[(k << 9) + m] = h;
        Dcm[(m << 9) + k] = h;
    }

    __shared__ float t[32][33];
    const long long base = (long long)blockIdx.z * IMG;
    const int r0 = blockIdx.y * 32, c0 = blockIdx.x * 32;
    const int tr = threadIdx.x >> 3;
    const int tc = (threadIdx.x & 7) * 4;
    float4 v = *(const float4*)&x[base + (long long)(r0 + tr) * N + c0 + tc];
    *(float4*)&outLL[base + (long long)(r0 + tr) * N + c0 + tc] = v;
    t[tr][tc + 0] = v.x; t[tr][tc + 1] = v.y;
    t[tr][tc + 2] = v.z; t[tr][tc + 3] = v.w;
    __syncthreads();
    ushort4 h;
    h.x = f2h(t[tc + 0][tr]); h.y = f2h(t[tc + 1][tr]);
    h.z = f2h(t[tc + 2][tr]); h.w = f2h(t[tc + 3][tr]);
    *(ushort4*)&Xcm[base + (long long)(c0 + tr) * N + r0 + tc] = h;
}

// ===========================================================================
// Proven GEMM engine (round-6, 349.6us): 128x128 tile, BK=32, 4 waves,
// dbuf LDS, global_load_lds width-16 staging, mfma_f32_16x16x32_f16,
// 2-barrier __syncthreads loop.
// C = A(row-major) * B(col-major storage: stored[n][k] = op(B)[k][n]).
// ===========================================================================
#define GEMM_DECLS                                                         \
    const int tid = threadIdx.x;                                           \
    const int wave = tid >> 6;                                             \
    const int lane = tid & 63;                                             \
    const int srow = lane >> 2;                                            \
    const int sc8  = (lane & 3) * 8;                                       \
    const int war  = wave * 32;                                            \
    const int fr   = lane & 15;                                            \
    const int kg8  = (lane >> 4) * 8;                                      \
    const int wr   = (wave >> 1) * 64;                                     \
    const int wc   = (wave & 1) * 64;                                      \
    const int rb   = (lane >> 4) * 4;                                      \
    int aoff[4], boff[4];                                                  \
    _Pragma("unroll")                                                      \
    for (int i = 0; i < 4; ++i) {                                          \
        aoff[i] = (wr + i * 16 + fr) * 32 + kg8;                           \
        boff[i] = (wc + i * 16 + fr) * 32 + kg8;                           \
    }                                                                      \
    f32x4 acc[4][4];                                                       \
    _Pragma("unroll")                                                      \
    for (int i = 0; i < 4; ++i)                                            \
        _Pragma("unroll")                                                  \
        for (int j = 0; j < 4; ++j)                                        \
            acc[i][j] = (f32x4){0.0f, 0.0f, 0.0f, 0.0f};

#define GEMM_LOOP(Ab, lda, Bb, ldb, Keff)                                  \
    {                                                                      \
        auto stage = [&](int buf, int k0) {                                \
            _Pragma("unroll")                                              \
            for (int i = 0; i < 2; ++i) {                                  \
                int r = war + i * 16;                                      \
                gload16((Ab) + (long long)(m0 + r + srow) * (lda) + k0 + sc8, &As[buf][r * 32]); \
                gload16((Bb) + (long long)(n0 + r + srow) * (ldb) + k0 + sc8, &Bs[buf][r * 32]); \
            }                                                              \
        };                                                                 \
        auto compute = [&](int buf) {                                      \
            f16x8 af[4], bf[4];                                            \
            _Pragma("unroll")                                              \
            for (int i = 0; i < 4; ++i) af[i] = *(const f16x8*)&As[buf][aoff[i]]; \
            _Pragma("unroll")                                              \
            for (int j = 0; j < 4; ++j) bf[j] = *(const f16x8*)&Bs[buf][boff[j]]; \
            _Pragma("unroll")                                              \
            for (int i = 0; i < 4; ++i)                                    \
                _Pragma("unroll")                                          \
                for (int j = 0; j < 4; ++j)                                \
                    acc[i][j] = __builtin_amdgcn_mfma_f32_16x16x32_f16(af[i], bf[j], acc[i][j], 0, 0, 0); \
        };                                                                 \
        const int nb = (Keff) >> 5;                                        \
        stage(0, 0);                                                       \
        __syncthreads();                                                   \
        int cur = 0;                                                       \
        for (int t = 0; t < nb - 1; ++t) {                                 \
            stage(cur ^ 1, (t + 1) * 32);                                  \
            compute(cur);                                                  \
            __syncthreads();                                               \
            cur ^= 1;                                                      \
        }                                                                  \
        compute(cur);                                                      \
    }

// ---------------------------------------------------------------------------
// gemm16: EPI 0 = fp32 row-major; 1 = f16 row-major;
// 3 = f16 col-major + tri mask + fused Y2/Y3 sub-blocks + zero-tile skip.
// ---------------------------------------------------------------------------
template<int EPI>
__global__ __launch_bounds__(256) void gemm16(
    const u16* __restrict__ A, long long sA, int lda,
    const u16* __restrict__ B, long long sB, int ldb,
    void* __restrict__ Cv, long long sC, int ldc,
    int K, int trilim,
    u16* __restrict__ Y2, u16* __restrict__ Y3)
{
    __shared__ u16 As[2][128 * 32];
    __shared__ u16 Bs[2][128 * 32];
    const int bz = blockIdx.z;
    const int m0 = blockIdx.y * 128;
    const int n0 = blockIdx.x * 128;

    if (EPI == 3 && (m0 + n0 > trilim)) return;   // fully-masked tile: never read downstream

    const u16* __restrict__ Ab = A + (long long)bz * sA;
    const u16* __restrict__ Bb = B + (long long)bz * sB;

    GEMM_DECLS
    GEMM_LOOP(Ab, lda, Bb, ldb, K)

    if (EPI == 0) {
        float* Cb = (float*)Cv + (long long)bz * sC;
        #pragma unroll
        for (int i = 0; i < 4; ++i)
            #pragma unroll
            for (int j = 0; j < 4; ++j) {
                int r = m0 + wr + i * 16 + rb;
                int c = n0 + wc + j * 16 + fr;
                #pragma unroll
                for (int g = 0; g < 4; ++g)
                    Cb[(long long)(r + g) * ldc + c] = acc[i][j][g];
            }
    } else if (EPI == 1) {
        u16* Cb = (u16*)Cv + (long long)bz * sC;
        #pragma unroll
        for (int i = 0; i < 4; ++i)
            #pragma unroll
            for (int j = 0; j < 4; ++j) {
                int r = m0 + wr + i * 16 + rb;
                int c = n0 + wc + j * 16 + fr;
                #pragma unroll
                for (int g = 0; g < 4; ++g)
                    Cb[(long long)(r + g) * ldc + c] = f2h(acc[i][j][g]);
            }
    } else {
        u16* Cb = (u16*)Cv + (long long)bz * sC;
        u16* Y2b = Y2 + (long long)bz * (256 * 256);
        u16* Y3b = Y3 + (long long)bz * (128 * 128);
        const bool doY2 = (m0 + n0 < 256);        // Y2 zero quadrant never read (kcap)
        #pragma unroll
        for (int i = 0; i < 4; ++i)
            #pragma unroll
            for (int j = 0; j < 4; ++j) {
                int r = m0 + wr + i * 16 + rb;
                int c = n0 + wc + j * 16 + fr;
                float v0 = ((r + 0) + c <= trilim) ? acc[i][j][0] : 0.0f;
                float v1 = ((r + 1) + c <= trilim) ? acc[i][j][1] : 0.0f;
                float v2 = ((r + 2) + c <= trilim) ? acc[i][j][2] : 0.0f;
                float v3 = ((r + 3) + c <= trilim) ? acc[i][j][3] : 0.0f;
                ushort4 h;
                h.x = f2h(v0); h.y = f2h(v1); h.z = f2h(v2); h.w = f2h(v3);
                *(ushort4*)&Cb[(long long)c * ldc + r] = h;   // col-major 8B store
                if (doY2 && r < 256 && c < 256) {
                    ushort4 h2;
                    h2.x = ((r + 0) + c <= 255) ? h.x : (u16)0;
                    h2.y = ((r + 1) + c <= 255) ? h.y : (u16)0;
                    h2.z = ((r + 2) + c <= 255) ? h.z : (u16)0;
                    h2.w = ((r + 3) + c <= 255) ? h.w : (u16)0;
                    *(ushort4*)&Y2b[(long long)c * 256 + r] = h2;
                }
                if (r < 128 && c < 128) {
                    ushort4 h3;
                    h3.x = ((r + 0) + c <= 127) ? h.x : (u16)0;
                    h3.y = ((r + 1) + c <= 127) ? h.y : (u16)0;
                    h3.z = ((r + 2) + c <= 127) ? h.z : (u16)0;
                    h3.w = ((r + 3) + c <= 127) ? h.w : (u16)0;
                    *(ushort4*)&Y3b[(long long)c * 128 + r] = h3;
                }
            }
    }
}

// ---------------------------------------------------------------------------
// invA: merged S3/S5/S7. Flat blockIdx.x in [0,28): [0,16)=S3, [16,24)=S5,
// [24,28)=S7. All write f16 col-major (= U* row-major). A anti-triangular ->
// K early stop (Keff).
// ---------------------------------------------------------------------------
__global__ __launch_bounds__(256) void invA(
    const u16* __restrict__ Ycm, const u16* __restrict__ Y2,
    const u16* __restrict__ Y3, const u16* __restrict__ Dcm,
    u16* __restrict__ U, u16* __restrict__ U2, u16* __restrict__ U3)
{
    __shared__ u16 As[2][128 * 32];
    __shared__ u16 Bs[2][128 * 32];
    const int bz = blockIdx.z;
    const int id = blockIdx.x;

    const u16* __restrict__ Ab;
    u16* __restrict__ Cb;
    int lda, ldc, Keff, m0, n0;
    if (id < 16) {            // S3: U^T = Ym^T @ D   (M=512, K=512-m0)
        m0 = (id >> 2) * 128; n0 = (id & 3) * 128;
        Ab = Ycm + (long long)bz * IMG;     lda = 512;
        Cb = U   + (long long)bz * IMG;     ldc = 512;
        Keff = 512 - m0;
    } else if (id < 24) {     // S5: U2^T = Y2^T @ D[:256,:]  (M=256, K=256-m0)
        int t = id - 16;
        m0 = (t >> 2) * 128; n0 = (t & 3) * 128;
        Ab = Y2 + (long long)bz * 65536;    lda = 256;
        Cb = U2 + (long long)bz * 131072;   ldc = 256;
        Keff = 256 - m0;
    } else {                  // S7: U3^T = Y3^T @ D[:128,:]  (M=128, K=128)
        int t = id - 24;
        m0 = 0;              n0 = (t & 3) * 128;
        Ab = Y3 + (long long)bz * 16384;    lda = 128;
        Cb = U3 + (long long)bz * 65536;    ldc = 128;
        Keff = 128;
    }
    const u16* __restrict__ Bb = Dcm;
    const int ldb = 512;

    GEMM_DECLS
    GEMM_LOOP(Ab, lda, Bb, ldb, Keff)

    #pragma unroll
    for (int i = 0; i < 4; ++i)
        #pragma unroll
        for (int j = 0; j < 4; ++j) {
            int r = m0 + wr + i * 16 + rb;
            int c = n0 + wc + j * 16 + fr;
            ushort4 h;
            h.x = f2h(acc[i][j][0]); h.y = f2h(acc[i][j][1]);
            h.z = f2h(acc[i][j][2]); h.w = f2h(acc[i][j][3]);
            *(ushort4*)&Cb[(long long)c * ldc + r] = h;
        }
}

// ---------------------------------------------------------------------------
// invC: merged S6/S8/S4 (all second-stage inverses; mutually independent,
// all read ws scratch only, write disjoint d_out quarters). fp32 row-major.
// Flat blockIdx.x in [0,48): [0,16)=S6 (HL = U2 @ D[:256,:], K=256),
// [16,32)=S8 (LH = U3 @ D[:128,:], K=128), [32,48)=S4 (HH = U @ D, K=512).
// ---------------------------------------------------------------------------
__global__ __launch_bounds__(256) void invC(
    const u16* __restrict__ U2, const u16* __restrict__ U3,
    const u16* __restrict__ U, const u16* __restrict__ Dcm,
    float* __restrict__ outHL, float* __restrict__ outLH,
    float* __restrict__ outHH)
{
    __shared__ u16 As[2][128 * 32];
    __shared__ u16 Bs[2][128 * 32];
    const int bz = blockIdx.z;
    const int id = blockIdx.x;

    const u16* __restrict__ Ab;
    float* __restrict__ Cb;
    int lda, Keff, m0, n0;
    if (id < 16) {            // S6: HL
        m0 = (id >> 2) * 128; n0 = (id & 3) * 128;
        Ab = U2 + (long long)bz * 131072;  lda = 256; Keff = 256;
        Cb = outHL + (long long)bz * IMG;
    } else if (id < 32) {     // S8: LH
        int t = id - 16;
        m0 = (t >> 2) * 128; n0 = (t & 3) * 128;
        Ab = U3 + (long long)bz * 65536;   lda = 128; Keff = 128;
        Cb = outLH + (long long)bz * IMG;
    } else {                  // S4: HH
        int t = id - 32;
        m0 = (t >> 2) * 128; n0 = (t & 3) * 128;
        Ab = U + (long long)bz * IMG;      lda = 512; Keff = 512;
        Cb = outHH + (long long)bz * IMG;
    }
    const u16* __restrict__ Bb = Dcm;
    const int ldb = 512;
    const int ldc = 512;

    GEMM_DECLS
    GEMM_LOOP(Ab, lda, Bb, ldb, Keff)

    #pragma unroll
    for (int i = 0; i < 4; ++i)
        #pragma unroll
        for (int j = 0; j < 4; ++j) {
            int r = m0 + wr + i * 16 + rb;
            int c = n0 + wc + j * 16 + fr;
            #pragma unroll
            for (int g = 0; g < 4; ++g)
                Cb[(long long)(r + g) * ldc + c] = acc[i][j][g];
        }
}

// ---------------------------------------------------------------------------
// Orchestration (5 dispatches): conv -> S1 -> S2 -> invA -> invC.
// ws layout (all scratch in ws; poison-fill evidence shows ws_size ~1.5GiB,
// we use 148MiB):
//   Drm @0 (512K) | Dcm @512K (512K) | Xcm/Ycm @1MiB (48MiB) |
//   reg @49MiB (48MiB): T1 (S1->S2) then U (invA->invC) |
//   Y2 @97MiB (12MiB) | Y3 @109MiB (3MiB) | U2 @112MiB (24MiB) | U3 @136MiB (12MiB)
// Race-freedom: invA reads Ycm/Y2/Y3, writes U/U2/U3 (disjoint); invC reads
// U/U2/U3 (read-only), writes the three d_out quarters (disjoint).
// ---------------------------------------------------------------------------
extern "C" void kernel_launch(void* const* d_in, const int* in_sizes, int n_in,
                              void* d_out, int out_size, void* d_ws, size_t ws_size,
                              hipStream_t stream) {
    const float* x = (const float*)d_in[0];
    float* out = (float*)d_out;
    float* outLL = out + 0 * OUT_PLANE;
    float* outLH = out + 1 * OUT_PLANE;
    float* outHL = out + 2 * OUT_PLANE;
    float* outHH = out + 3 * OUT_PLANE;

    char* ws = (char*)d_ws;
    u16* Drm = (u16*)(ws);
    u16* Dcm = (u16*)(ws + 524288);
    u16* Xcm = (u16*)(ws + 1048576);
    u16* Ycm = Xcm;
    char* reg = ws + 51380224;
    u16* T1 = (u16*)reg;
    u16* U  = (u16*)reg;
    u16* Y2 = (u16*)(ws + 101711872);      // 96*256*256 f16 = 12 MiB
    u16* Y3 = (u16*)(ws + 114294784);      // 96*128*128 f16 = 3 MiB
    u16* U2 = (u16*)(ws + 117440512);      // 96*512*256 f16 = 24 MiB
    u16* U3 = (u16*)(ws + 142606336);      // 96*512*128 f16 = 12 MiB (ends 148MiB)

    const long long S = IMG;
    const int BIG = 1 << 30;

    // conv + D-build + LL copy
    conv_x<<<dim3(16, 16, NIMG), 256, 0, stream>>>(x, Xcm, outLL, Drm, Dcm);

    // S1: T1 = D @ X -> f16 row-major
    gemm16<1><<<dim3(4, 4, NIMG), 256, 0, stream>>>(
        Drm, 0, 512, Xcm, S, 512, T1, S, 512, 512, BIG, nullptr, nullptr);
    // S2: Y = T1 @ D^T -> Ycm (tri511, fully-masked tiles skipped) + Y2/Y3
    gemm16<3><<<dim3(4, 4, NIMG), 256, 0, stream>>>(
        T1, S, 512, Drm, 0, 512, Ycm, S, 512, 512, 511, Y2, Y3);
    // invA: S3 + S5 + S7 -> U, U2, U3 (all ws)
    invA<<<dim3(28, 1, NIMG), 256, 0, stream>>>(Ycm, Y2, Y3, Dcm, U, U2, U3);
    // invC: S6 + S8 + S4 -> outHL, outLH, outHH
    invC<<<dim3(48, 1, NIMG), 256, 0, stream>>>(U2, U3, U, Dcm, outHL, outLH, outHH);
}